// Round 11
// baseline (102.879 us; speedup 1.0000x reference)
//
#include <hip/hip_runtime.h>
#include <hip/hip_bf16.h>

typedef __attribute__((ext_vector_type(8))) short bf16x8;
typedef __attribute__((ext_vector_type(4))) float f32x4;

#define CIN   128
#define COUT  256
#define NIMG  32
#define HWDIM 56
#define HPAD  58
#define KTOT  1152            // 9*128
#define HWIMG 3136
#define MTOT  100352
#define BK    128             // one full tap per K-step
#define NT    9

__device__ __forceinline__ void gload16(const void* g, void* l) {
  __builtin_amdgcn_global_load_lds((const __attribute__((address_space(1))) void*)g,
                                   (__attribute__((address_space(3))) void*)l,
                                   16, 0, 0);
}

// ---------------- fused pre-pass: halo zero + x->NHWC bf16 + sign(w) ------
__global__ __launch_bounds__(256)
void prep_all(const float* __restrict__ x, const float* __restrict__ w,
              __hip_bfloat16* __restrict__ xp, __hip_bfloat16* __restrict__ wt) {
  __shared__ float tile[CIN * 57];
  const int bid = blockIdx.x;
  const int t = threadIdx.x;
  if (bid < NIMG * HPAD) {
    const int n = bid / HPAD;
    const int h = bid - n * HPAD;
    __hip_bfloat16* dstrow = xp + ((size_t)n * HPAD + h) * HPAD * CIN;
    int4 z; z.x = 0; z.y = 0; z.z = 0; z.w = 0;
    if (h == 0 || h == HPAD - 1) {
      for (int i = t; i < (HPAD * CIN) / 8; i += 256)
        reinterpret_cast<int4*>(dstrow)[i] = z;
      return;
    }
    const float* src = x + (size_t)n * CIN * HWIMG + (size_t)(h - 1) * HWDIM;
    for (int i = t; i < CIN * HWDIM; i += 256) {
      int c = i / HWDIM;
      int wd = i - c * HWDIM;
      tile[c * 57 + wd] = src[(size_t)c * HWIMG + wd];
    }
    if (t < 32) {
      int side = t >> 4;
      reinterpret_cast<int4*>(dstrow + (side ? (HPAD - 1) : 0) * CIN)[t & 15] = z;
    }
    __syncthreads();
    // vectorized xp writes: short8 (16B) per (wd, 8-channel chunk)
    __hip_bfloat16* dst = dstrow + CIN;    // col 1
    for (int o = t; o < HWDIM * 16; o += 256) {
      int wd = o >> 4;
      int c8 = (o & 15) * 8;
      bf16x8 v;
#pragma unroll
      for (int j = 0; j < 8; ++j)
        v[j] = (short)__bfloat16_as_ushort(__float2bfloat16(tile[(c8 + j) * 57 + wd]));
      *reinterpret_cast<bf16x8*>(dst + (size_t)wd * CIN + c8) = v;
    }
  } else {
    int o = (bid - NIMG * HPAD) * 256 + t;
    int cout = o / KTOT;
    int r = o - cout * KTOT;
    int tap = r >> 7;
    int cin = r & 127;
    float v = w[((size_t)cout * CIN + cin) * 9 + tap];
    wt[o] = __float2bfloat16(v > 0.f ? 1.f : (v < 0.f ? -1.f : 0.f));
  }
}

// ---------------- main: 128x128 tile, BK=128 (one tap/step), R5 schedule --
__global__ __launch_bounds__(256, 2)
void bconv(const short* __restrict__ xp, const short* __restrict__ wt,
           const float* __restrict__ bias, float* __restrict__ out) {
  __shared__ short lw[128 * BK];   // 32 KB (A: weights)
  __shared__ short lx[128 * BK];   // 32 KB (B: x)

  const int tid  = threadIdx.x;
  const int lane = tid & 63;
  const int wv   = tid >> 6;      // 0..3
  const int wm   = wv >> 1;       // cout half
  const int wn   = wv & 1;        // spatial half

  // bijective XCD swizzle (1568 % 8 == 0): L2 locality for xp
  const int myid = blockIdx.y * 784 + blockIdx.x;
  const int sid  = (myid & 7) * 196 + (myid >> 3);
  const int s0   = (sid >> 1) * 128;
  const int f0   = (sid & 1) * 128;

  // staging: 16 slots/row, 16 rows/round, 8 rounds per region
  const int srow = tid >> 4;      // 0..15
  const int slot = tid & 15;
  const int swz  = (slot & 8) | ((slot & 7) ^ (srow & 7));

  int xoff[8];
  int woff[8];
#pragma unroll
  for (int r = 0; r < 8; ++r) {
    int m  = s0 + r * 16 + srow;
    int n  = m / HWIMG;
    int hw = m - n * HWIMG;
    int h  = hw / HWDIM;
    int w  = hw - h * HWDIM;
    xoff[r] = ((n * HPAD + h) * HPAD + w) * CIN + swz * 8;   // cin = swz*8
    woff[r] = (f0 + r * 16 + srow) * KTOT + swz * 8;
  }

  f32x4 acc[4][4] = {};

  const int rlo = lane & 15;
  const int kq  = lane >> 4;      // 0..3
  const int swr = rlo & 7;

  for (int t = 0; t < NT; ++t) {   // t == tap
    const int kh  = t / 3;
    const int kw  = t - kh * 3;
    const int xko = (kh * HPAD + kw) * CIN;
    const int wko = t * BK;

    __syncthreads();   // previous compute done before overwriting LDS
#pragma unroll
    for (int r = 0; r < 8; ++r) {
      gload16(wt + woff[r] + wko, &lw[(r * 16 + wv * 4) * BK]);
      gload16(xp + xoff[r] + xko, &lx[(r * 16 + wv * 4) * BK]);
    }
    __syncthreads();   // drain -> tiles ready

#pragma unroll
    for (int ksub = 0; ksub < 4; ++ksub) {
      const int ch = ksub * 4 + kq;                       // 0..15
      const int sx = (ch & 8) | ((ch & 7) ^ swr);
      bf16x8 af[4], bx[4];
#pragma unroll
      for (int f = 0; f < 4; ++f)
        af[f] = *(const bf16x8*)&lw[(wm * 64 + f * 16 + rlo) * BK + sx * 8];
#pragma unroll
      for (int f = 0; f < 4; ++f)
        bx[f] = *(const bf16x8*)&lx[(wn * 64 + f * 16 + rlo) * BK + sx * 8];
      // swapped operands: D rows = spatial (bx), cols = cout (af)
#pragma unroll
      for (int fm = 0; fm < 4; ++fm)
#pragma unroll
        for (int fn = 0; fn < 4; ++fn)
          acc[fm][fn] = __builtin_amdgcn_mfma_f32_16x16x32_bf16(
              bx[fn], af[fm], acc[fm][fn], 0, 0, 0);
    }
  }

  // epilogue: D rows = spatial (rg*4+j consecutive hw), cols = cout (lane&15)
  const int col = lane & 15;
  const int rg  = lane >> 4;
  int nb[4], hwb[4];
#pragma unroll
  for (int fn = 0; fn < 4; ++fn) {
    int m16 = s0 + wn * 64 + fn * 16;    // 16-aligned; 3136 % 16 == 0
    int n = m16 / HWIMG;
    nb[fn]  = n;
    hwb[fn] = m16 - n * HWIMG + rg * 4;
  }
#pragma unroll
  for (int fm = 0; fm < 4; ++fm) {
    int cc = f0 + wm * 64 + fm * 16 + col;
    float bv = bias[cc];
#pragma unroll
    for (int fn = 0; fn < 4; ++fn) {
      float4 v;
      v.x = acc[fm][fn][0] + bv;
      v.y = acc[fm][fn][1] + bv;
      v.z = acc[fm][fn][2] + bv;
      v.w = acc[fm][fn][3] + bv;
      *reinterpret_cast<float4*>(out + ((size_t)nb[fn] * COUT + cc) * HWIMG + hwb[fn]) = v;
    }
  }
}

extern "C" void kernel_launch(void* const* d_in, const int* in_sizes, int n_in,
                              void* d_out, int out_size, void* d_ws, size_t ws_size,
                              hipStream_t stream) {
  const float* x = (const float*)d_in[0];
  const float* w = (const float*)d_in[1];
  const float* b = (const float*)d_in[2];
  float* out = (float*)d_out;

  const size_t xp_elems = (size_t)NIMG * HPAD * HPAD * CIN;
  __hip_bfloat16* xp = (__hip_bfloat16*)d_ws;
  __hip_bfloat16* wt = xp + xp_elems;

  prep_all<<<NIMG * HPAD + (COUT * KTOT) / 256, 256, 0, stream>>>(x, w, xp, wt);

  dim3 grid(MTOT / 128, COUT / 128);
  bconv<<<grid, 256, 0, stream>>>((const short*)xp, (const short*)wt, b, out);
}